// Round 1
// baseline (214.827 us; speedup 1.0000x reference)
//
#include <hip/hip_runtime.h>

#define IN_CH 128
#define OUT_CH 64
#define NEG_SLOPE 0.2f
// p0 accumulated as 20-bit fixed point in low 32 bits, edge count in high 32.
#define FIX20 1048576.0f

typedef short bf16x8 __attribute__((ext_vector_type(8)));
typedef float f32x4 __attribute__((ext_vector_type(4)));
typedef int i32x4 __attribute__((ext_vector_type(4)));
typedef unsigned long long u64;
typedef unsigned int u32;

__device__ __forceinline__ unsigned short f2bf(float f) {
  union { float f; unsigned u; } v;
  v.f = f;
  unsigned r = v.u + 0x7FFF + ((v.u >> 16) & 1);  // RNE
  return (unsigned short)(r >> 16);
}

// ---------------------------------------------------------------------------
// Kernel 0 (prep): 66 blocks.
//  bid<64: lwt[c][k] = bf16(lw[k][c]) (transposed 32 KB bf16 B^T table).
//  bid 64/65: u_i / u_j (512 floats): u[which*256 + h*128 + k] = lw[k,:].att_h
// ---------------------------------------------------------------------------
__global__ __launch_bounds__(256) void prep_kernel(
    const float* __restrict__ lw, const float* __restrict__ att_i,
    const float* __restrict__ att_j, unsigned short* __restrict__ lwt,
    float* __restrict__ u) {
  const int bid = blockIdx.x;
  const int tid = threadIdx.x;
  if (bid < 64) {
    int idx = bid * 256 + tid;  // 0..16383
    int k = idx >> 7;
    int c = idx & 127;
    lwt[(size_t)c * IN_CH + k] = f2bf(lw[idx]);
  } else {
    int which = bid - 64;  // 0 -> att_i, 1 -> att_j
    const float* att = which ? att_j : att_i;
    int k = tid & 127;
    int h = (tid >> 7) & 1;
    float v = 0.f;
#pragma unroll 8
    for (int d = 0; d < 64; ++d)
      v = fmaf(lw[(size_t)k * IN_CH + h * 64 + d], att[h * 64 + d], v);
    u[which * 256 + h * 128 + k] = v;
  }
}

// ---------------------------------------------------------------------------
// Kernel 1 (score): si/sj/wself from x,emb via precomputed u (L1-hot 2 KB).
// Seeds wsum64=0. One wave per node.
// ---------------------------------------------------------------------------
__global__ __launch_bounds__(256) void score_kernel(
    const float* __restrict__ x, const float* __restrict__ emb,
    const float* __restrict__ u, const float* __restrict__ aei,
    const float* __restrict__ aej, float2* __restrict__ si,
    float2* __restrict__ sj, float* __restrict__ wself,
    u64* __restrict__ wsum64, int N) {
  const int tid = threadIdx.x;
  const int wave = tid >> 6;
  const int lane = tid & 63;
  const int n = blockIdx.x * 4 + wave;
  if (n >= N) return;

  float x0 = x[(size_t)n * IN_CH + lane];
  float x1 = x[(size_t)n * IN_CH + 64 + lane];
  float em = emb[(size_t)n * OUT_CH + lane];

  float v_si0 = fmaf(x0, u[lane], fmaf(x1, u[64 + lane], em * aei[lane]));
  float v_si1 =
      fmaf(x0, u[128 + lane], fmaf(x1, u[192 + lane], em * aei[64 + lane]));
  float v_sj0 =
      fmaf(x0, u[256 + lane], fmaf(x1, u[320 + lane], em * aej[lane]));
  float v_sj1 =
      fmaf(x0, u[384 + lane], fmaf(x1, u[448 + lane], em * aej[64 + lane]));

#pragma unroll
  for (int off = 32; off > 0; off >>= 1) {
    v_si0 += __shfl_xor(v_si0, off, 64);
    v_si1 += __shfl_xor(v_si1, off, 64);
    v_sj0 += __shfl_xor(v_sj0, off, 64);
    v_sj1 += __shfl_xor(v_sj1, off, 64);
  }

  if (lane == 0) {
    si[n] = make_float2(v_si0, v_si1);
    sj[n] = make_float2(v_sj0, v_sj1);
    float a0 = v_si0 + v_sj0;
    float a1 = v_si1 + v_sj1;
    a0 = a0 > 0.f ? a0 : NEG_SLOPE * a0;
    a1 = a1 > 0.f ? a1 : NEG_SLOPE * a1;
    wself[n] = 1.f / (1.f + __expf(a1 - a0));
    wsum64[n] = 0ull;  // baseline for edge accumulation
  }
}

// ---------------------------------------------------------------------------
// Kernel 2 (edges): 4 edges/thread. One packed u64 device atomic per edge:
//   wsum64[d] += (1<<32) | fix20(p0)   (count in hi32, sum p0 in lo32).
// No LDS, no barriers; latency hidden by full occupancy + 4-deep ILP.
// ---------------------------------------------------------------------------
__global__ __launch_bounds__(256) void edge_kernel(
    const int* __restrict__ esrc, const int* __restrict__ edst,
    const float2* __restrict__ si, const float2* __restrict__ sj,
    u64* __restrict__ wsum64, int E) {
  const int t = blockIdx.x * 256 + threadIdx.x;
  const long base = (long)t * 4;
  if (base + 4 <= E) {
    i32x4 s4 = __builtin_nontemporal_load((const i32x4*)(esrc + base));
    i32x4 d4 = __builtin_nontemporal_load((const i32x4*)(edst + base));
    float2 aa[4], bb[4];
#pragma unroll
    for (int k = 0; k < 4; ++k) {
      aa[k] = si[s4[k]];
      bb[k] = sj[d4[k]];
    }
#pragma unroll
    for (int k = 0; k < 4; ++k) {
      float a0 = aa[k].x + bb[k].x;
      float a1 = aa[k].y + bb[k].y;
      a0 = a0 > 0.f ? a0 : NEG_SLOPE * a0;
      a1 = a1 > 0.f ? a1 : NEG_SLOPE * a1;
      float p0 = 1.f / (1.f + __expf(a1 - a0));
      u32 fx = (u32)fminf(p0 * FIX20 + 0.5f, 1048575.0f);
      atomicAdd(&wsum64[d4[k]], (1ull << 32) | (u64)fx);
    }
  } else if (base < E) {
    for (long e = base; e < E; ++e) {
      int s = esrc[e];
      int d = edst[e];
      float2 aa = si[s];
      float2 bb = sj[d];
      float a0 = aa.x + bb.x;
      float a1 = aa.y + bb.y;
      a0 = a0 > 0.f ? a0 : NEG_SLOPE * a0;
      a1 = a1 > 0.f ? a1 : NEG_SLOPE * a1;
      float p0 = 1.f / (1.f + __expf(a1 - a0));
      u32 fx = (u32)fminf(p0 * FIX20 + 0.5f, 1048575.0f);
      atomicAdd(&wsum64[d], (1ull << 32) | (u64)fx);
    }
  }
}

// ---------------------------------------------------------------------------
// Kernel 3 (gemm + out, fused epilogue): xh = x @ lin_w via
// mfma_16x16x32_bf16 (B^T from L1-resident 32 KB lwt table), then apply
// per-node head weights from wsum64/wself and write out directly.
// xh never touches memory: saves 51 MB of traffic + a whole kernel.
// ---------------------------------------------------------------------------
__global__ __launch_bounds__(256) void gemm_out_kernel(
    const float* __restrict__ x, const unsigned short* __restrict__ lwt,
    const u64* __restrict__ wsum64, const float* __restrict__ wself,
    float* __restrict__ out, int N) {
  const int tid = threadIdx.x;
  const int wave = tid >> 6;
  const int lane = tid & 63;
  const int ko = (lane >> 4) * 8;
  const int ccol = lane & 15;
  const int row0 = blockIdx.x * 64 + wave * 16;

  int arow = row0 + (lane & 15);
  if (arow >= N) arow = N - 1;  // clamped read; stores guarded
  const float* ap = x + (size_t)arow * IN_CH + ko;
  bf16x8 a[4];
#pragma unroll
  for (int kb = 0; kb < 4; ++kb) {
    float4 f0 = *(const float4*)(ap + kb * 32);
    float4 f1 = *(const float4*)(ap + kb * 32 + 4);
    bf16x8 t;
    t[0] = (short)f2bf(f0.x); t[1] = (short)f2bf(f0.y);
    t[2] = (short)f2bf(f0.z); t[3] = (short)f2bf(f0.w);
    t[4] = (short)f2bf(f1.x); t[5] = (short)f2bf(f1.y);
    t[6] = (short)f2bf(f1.z); t[7] = (short)f2bf(f1.w);
    a[kb] = t;
  }

  const int crow0 = row0 + (lane >> 4) * 4;
  // per-row head weights (0.5 head-mean folded in)
  float w0r[4], w1r[4];
#pragma unroll
  for (int rr = 0; rr < 4; ++rr) {
    int n = crow0 + rr;
    if (n >= N) n = N - 1;
    u64 acc = wsum64[n];
    float cnt = (float)(u32)(acc >> 32);
    float s0 = (float)(u32)(acc & 0xFFFFFFFFu) * (1.0f / FIX20);
    float ps = wself[n];
    w0r[rr] = 0.5f * (s0 + ps);
    w1r[rr] = 0.5f * ((cnt - s0) + (1.f - ps));
  }

#pragma unroll
  for (int nt = 0; nt < 4; ++nt) {
    f32x4 acc0 = {0.f, 0.f, 0.f, 0.f};  // head0 col nt*16+ccol
    f32x4 acc1 = {0.f, 0.f, 0.f, 0.f};  // head1 col 64+nt*16+ccol
    const bf16x8* bp0 =
        (const bf16x8*)(lwt + (size_t)(nt * 16 + ccol) * IN_CH + ko);
    const bf16x8* bp1 =
        (const bf16x8*)(lwt + (size_t)(64 + nt * 16 + ccol) * IN_CH + ko);
#pragma unroll
    for (int kb = 0; kb < 4; ++kb) {
      acc0 = __builtin_amdgcn_mfma_f32_16x16x32_bf16(a[kb], bp0[kb * 4], acc0,
                                                     0, 0, 0);
      acc1 = __builtin_amdgcn_mfma_f32_16x16x32_bf16(a[kb], bp1[kb * 4], acc1,
                                                     0, 0, 0);
    }
#pragma unroll
    for (int rr = 0; rr < 4; ++rr) {
      int n = crow0 + rr;
      if (n < N)
        out[(size_t)n * OUT_CH + nt * 16 + ccol] =
            fmaf(acc0[rr], w0r[rr], acc1[rr] * w1r[rr]);
    }
  }
}

extern "C" void kernel_launch(void* const* d_in, const int* in_sizes, int n_in,
                              void* d_out, int out_size, void* d_ws,
                              size_t ws_size, hipStream_t stream) {
  const float* x = (const float*)d_in[0];
  const float* emb = (const float*)d_in[1];
  const float* lw = (const float*)d_in[2];
  const float* att_i = (const float*)d_in[3];
  const float* att_j = (const float*)d_in[4];
  const float* aei = (const float*)d_in[5];
  const float* aej = (const float*)d_in[6];
  const int* esrc = (const int*)d_in[7];
  const int* edst = (const int*)d_in[8];
  float* out = (float*)d_out;

  int N = in_sizes[0] / IN_CH;  // 50000
  int E = in_sizes[7];          // 1600000

  char* ws = (char*)d_ws;
  u64* wsum64 = (u64*)ws;                              // N u64 (8B aligned)
  float2* si = (float2*)(wsum64 + N);                  // N float2
  float2* sj = si + N;                                 // N float2
  float* wself = (float*)(sj + N);                     // N f32
  float* u = wself + N;                                // 512 f32
  unsigned short* lwt = (unsigned short*)(u + 512);    // 16384 bf16 (32 KB)

  prep_kernel<<<dim3(66), dim3(256), 0, stream>>>(lw, att_i, att_j, lwt, u);
  score_kernel<<<dim3((N + 3) / 4), dim3(256), 0, stream>>>(
      x, emb, u, aei, aej, si, sj, wself, wsum64, N);
  edge_kernel<<<dim3((E + 1023) / 1024), dim3(256), 0, stream>>>(
      esrc, edst, si, sj, wsum64, E);
  gemm_out_kernel<<<dim3((N + 63) / 64), dim3(256), 0, stream>>>(
      x, lwt, wsum64, wself, out, N);
}

// Round 2
// 176.703 us; speedup vs baseline: 1.2157x; 1.2157x over previous
//
#include <hip/hip_runtime.h>

#define IN_CH 128
#define OUT_CH 64
#define NEG_SLOPE 0.2f

#define CHUNK 2048      // edges per bin block
#define BSHIFT 10       // 1024 nodes per partition
#define SPLITS 6        // acc blocks per partition
#define CAPMAX 36864    // records per partition region (mean 32.7K + ~23 sigma)
// p0 stored as 22-bit fixed point; u64 accumulate = (cnt<<32) | sum(fx22).
#define FIX22 4194304.0f

typedef short bf16x8 __attribute__((ext_vector_type(8)));
typedef float f32x4 __attribute__((ext_vector_type(4)));
typedef unsigned long long u64;
typedef unsigned int u32;

__device__ __forceinline__ unsigned short f2bf(float f) {
  union { float f; unsigned u; } v;
  v.f = f;
  unsigned r = v.u + 0x7FFF + ((v.u >> 16) & 1);  // RNE
  return (unsigned short)(r >> 16);
}

// ---------------------------------------------------------------------------
// Kernel 0 (prep): 66 blocks.
//  bid<64: lwt[c][k] = bf16(lw[k][c]) (transposed 32 KB bf16 B^T table).
//  bid 64/65: u_i / u_j (512 floats). bid 0 also zeroes bucket cursors.
// ---------------------------------------------------------------------------
__global__ __launch_bounds__(256) void prep_kernel(
    const float* __restrict__ lw, const float* __restrict__ att_i,
    const float* __restrict__ att_j, unsigned short* __restrict__ lwt,
    float* __restrict__ u, int* __restrict__ gcur) {
  const int bid = blockIdx.x;
  const int tid = threadIdx.x;
  if (bid == 0) gcur[tid] = 0;
  if (bid < 64) {
    int idx = bid * 256 + tid;  // 0..16383
    int k = idx >> 7;
    int c = idx & 127;
    lwt[(size_t)c * IN_CH + k] = f2bf(lw[idx]);
  } else {
    int which = bid - 64;  // 0 -> att_i, 1 -> att_j
    const float* att = which ? att_j : att_i;
    int k = tid & 127;
    int h = (tid >> 7) & 1;
    float v = 0.f;
#pragma unroll 8
    for (int d = 0; d < 64; ++d)
      v = fmaf(lw[(size_t)k * IN_CH + h * 64 + d], att[h * 64 + d], v);
    u[which * 256 + h * 128 + k] = v;
  }
}

// ---------------------------------------------------------------------------
// Kernel 1 (score): si/sj/wself from x,emb via precomputed u (L1-hot 2 KB).
// Seeds wsum64=0 (spill baseline). One wave per node.
// ---------------------------------------------------------------------------
__global__ __launch_bounds__(256) void score_kernel(
    const float* __restrict__ x, const float* __restrict__ emb,
    const float* __restrict__ u, const float* __restrict__ aei,
    const float* __restrict__ aej, float2* __restrict__ si,
    float2* __restrict__ sj, float* __restrict__ wself,
    u64* __restrict__ wsum64, int N) {
  const int tid = threadIdx.x;
  const int wave = tid >> 6;
  const int lane = tid & 63;
  const int n = blockIdx.x * 4 + wave;
  if (n >= N) return;

  float x0 = x[(size_t)n * IN_CH + lane];
  float x1 = x[(size_t)n * IN_CH + 64 + lane];
  float em = emb[(size_t)n * OUT_CH + lane];

  float v_si0 = fmaf(x0, u[lane], fmaf(x1, u[64 + lane], em * aei[lane]));
  float v_si1 =
      fmaf(x0, u[128 + lane], fmaf(x1, u[192 + lane], em * aei[64 + lane]));
  float v_sj0 =
      fmaf(x0, u[256 + lane], fmaf(x1, u[320 + lane], em * aej[lane]));
  float v_sj1 =
      fmaf(x0, u[384 + lane], fmaf(x1, u[448 + lane], em * aej[64 + lane]));

#pragma unroll
  for (int off = 32; off > 0; off >>= 1) {
    v_si0 += __shfl_xor(v_si0, off, 64);
    v_si1 += __shfl_xor(v_si1, off, 64);
    v_sj0 += __shfl_xor(v_sj0, off, 64);
    v_sj1 += __shfl_xor(v_sj1, off, 64);
  }

  if (lane == 0) {
    si[n] = make_float2(v_si0, v_si1);
    sj[n] = make_float2(v_sj0, v_sj1);
    float a0 = v_si0 + v_sj0;
    float a1 = v_si1 + v_sj1;
    a0 = a0 > 0.f ? a0 : NEG_SLOPE * a0;
    a1 = a1 > 0.f ? a1 : NEG_SLOPE * a1;
    wself[n] = 1.f / (1.f + __expf(a1 - a0));
    wsum64[n] = 0ull;  // spill-fallback baseline
  }
}

// ---------------------------------------------------------------------------
// Kernel 2 (bin): counting-sort a 2048-edge chunk into 49 dst-range buckets.
// LDS = 9.25 KB -> 8 blocks/CU. Single-wave shuffle scan (no 16-barrier
// Hillis-Steele), 6-iter binary search on writeout. Record =
// (dlocal10 << 22) | fx22(p0). Overflow -> packed u64 atomic into wsum64.
// ---------------------------------------------------------------------------
__global__ __launch_bounds__(256) void bin_kernel(
    const int* __restrict__ esrc, const int* __restrict__ edst,
    const float2* __restrict__ si, const float2* __restrict__ sj,
    u32* __restrict__ brecs, int* __restrict__ gcur,
    u64* __restrict__ wsum64, int cap, int E) {
  __shared__ u32 recs[CHUNK];  // 8 KB
  __shared__ int hist[64];
  __shared__ int scan[64];
  __shared__ int gbase[64];
  __shared__ int cur[64];
  const int bid = blockIdx.x;
  const int tid = threadIdx.x;

  if (tid < 64) hist[tid] = 0;
  __syncthreads();

  const long e0 = (long)bid * CHUNK;
  const int cnt = (int)min((long)CHUNK, (long)E - e0);

  for (int r = tid; r < cnt; r += 256)
    atomicAdd(&hist[edst[e0 + r] >> BSHIFT], 1);
  __syncthreads();

  // wave-0 shuffle prefix scan over 64 buckets
  if (tid < 64) {
    int h = hist[tid];
    int v = h;
#pragma unroll
    for (int off = 1; off < 64; off <<= 1) {
      int t = __shfl_up(v, off, 64);
      if (tid >= off) v += t;
    }
    int excl = v - h;  // exclusive scan; == cnt for empty tail buckets
    scan[tid] = excl;
    cur[tid] = excl;
    gbase[tid] = (h > 0) ? atomicAdd(&gcur[tid], h) : 0;
  }
  __syncthreads();

  // per-edge score -> scatter record into LDS grouped by bucket
  for (int r = tid; r < cnt; r += 256) {
    long e = e0 + r;
    int s = esrc[e];
    int d = edst[e];
    float2 aa = si[s];
    float2 bb = sj[d];
    float a0 = aa.x + bb.x;
    float a1 = aa.y + bb.y;
    a0 = a0 > 0.f ? a0 : NEG_SLOPE * a0;
    a1 = a1 > 0.f ? a1 : NEG_SLOPE * a1;
    float p0 = 1.f / (1.f + __expf(a1 - a0));
    u32 fx = (u32)fminf(p0 * FIX22 + 0.5f, 4194303.0f);  // 22-bit
    int pos = atomicAdd(&cur[d >> BSHIFT], 1);
    recs[pos] = ((u32)(d & 1023) << 22) | fx;
  }
  __syncthreads();

  // coalesced writeout; bucket via 6-iter binary search over scan
  for (int p = tid; p < cnt; p += 256) {
    int lo = 0, hi = 63;
#pragma unroll
    for (int it = 0; it < 6; ++it) {
      int mid = (lo + hi + 1) >> 1;
      if (scan[mid] <= p) lo = mid; else hi = mid - 1;
    }
    int b = lo;
    int gofs = gbase[b] + (p - scan[b]);
    u32 rec = recs[p];
    if (gofs < cap) {
      brecs[(size_t)b * cap + gofs] = rec;
    } else {  // rare spill: packed u64 device atomic
      atomicAdd(&wsum64[(b << BSHIFT) + (int)(rec >> 22)],
                (1ull << 32) | (u64)(rec & 0x3FFFFFu));
    }
  }
}

// ---------------------------------------------------------------------------
// Kernel 3 (acc): block (p,s) accumulates slice s of partition p's records
// into a 1024-entry u64 LDS table (cnt<<32 | sum fx22), then dumps the
// partial table non-atomically. 49*6 = 294 blocks, 8 KB LDS.
// ---------------------------------------------------------------------------
__global__ __launch_bounds__(256) void acc_kernel(
    const u32* __restrict__ brecs, const int* __restrict__ gcur,
    u64* __restrict__ ptabs, int cap) {
  __shared__ u64 tab[1024];  // 8 KB
  const int bid = blockIdx.x;
  const int tid = threadIdx.x;
  const int p = bid / SPLITS;
  const int s = bid - p * SPLITS;

  for (int i = tid; i < 1024; i += 256) tab[i] = 0ull;
  __syncthreads();

  const int cnt = min(gcur[p], cap);
  const int per = (cnt + SPLITS - 1) / SPLITS;
  const int lo = s * per;
  const int hi = min(lo + per, cnt);
  const u32* rp = brecs + (size_t)p * cap;
  for (int r = lo + tid; r < hi; r += 256) {
    u32 rec = rp[r];
    atomicAdd(&tab[rec >> 22], (1ull << 32) | (u64)(rec & 0x3FFFFFu));
  }
  __syncthreads();

  u64* op = ptabs + ((size_t)bid << 10);
  for (int i = tid; i < 1024; i += 256) op[i] = tab[i];
}

// ---------------------------------------------------------------------------
// Kernel 4 (gemm + out): xh = x @ lin_w via mfma_16x16x32_bf16 (B^T from the
// L1-resident 32 KB lwt table); epilogue sums the SPLITS partial tables +
// spill baseline + self-loop and writes out directly (xh never hits memory).
// ---------------------------------------------------------------------------
__global__ __launch_bounds__(256) void gemm_out_kernel(
    const float* __restrict__ x, const unsigned short* __restrict__ lwt,
    const u64* __restrict__ wsum64, const u64* __restrict__ ptabs,
    const float* __restrict__ wself, float* __restrict__ out, int N) {
  const int tid = threadIdx.x;
  const int wave = tid >> 6;
  const int lane = tid & 63;
  const int ko = (lane >> 4) * 8;
  const int ccol = lane & 15;
  const int row0 = blockIdx.x * 64 + wave * 16;

  int arow = row0 + (lane & 15);
  if (arow >= N) arow = N - 1;  // clamped read; stores guarded
  const float* ap = x + (size_t)arow * IN_CH + ko;
  bf16x8 a[4];
#pragma unroll
  for (int kb = 0; kb < 4; ++kb) {
    float4 f0 = *(const float4*)(ap + kb * 32);
    float4 f1 = *(const float4*)(ap + kb * 32 + 4);
    bf16x8 t;
    t[0] = (short)f2bf(f0.x); t[1] = (short)f2bf(f0.y);
    t[2] = (short)f2bf(f0.z); t[3] = (short)f2bf(f0.w);
    t[4] = (short)f2bf(f1.x); t[5] = (short)f2bf(f1.y);
    t[6] = (short)f2bf(f1.z); t[7] = (short)f2bf(f1.w);
    a[kb] = t;
  }

  const int crow0 = row0 + (lane >> 4) * 4;
  // per-row head weights: sum SPLITS partial tables + spill + self-loop
  float w0r[4], w1r[4];
#pragma unroll
  for (int rr = 0; rr < 4; ++rr) {
    int n = crow0 + rr;
    if (n >= N) n = N - 1;
    u64 acc = wsum64[n];
    const u64* pt = ptabs + (((size_t)(n >> BSHIFT) * SPLITS) << 10) + (n & 1023);
#pragma unroll
    for (int s5 = 0; s5 < SPLITS; ++s5) acc += pt[(size_t)s5 << 10];
    float cnt = (float)(u32)(acc >> 32);
    float s0 = (float)(u32)(acc & 0xFFFFFFFFu) * (1.0f / FIX22);
    float ps = wself[n];
    w0r[rr] = 0.5f * (s0 + ps);
    w1r[rr] = 0.5f * ((cnt - s0) + (1.f - ps));
  }

#pragma unroll
  for (int nt = 0; nt < 4; ++nt) {
    f32x4 acc0 = {0.f, 0.f, 0.f, 0.f};  // head0 col nt*16+ccol
    f32x4 acc1 = {0.f, 0.f, 0.f, 0.f};  // head1 col 64+nt*16+ccol
    const bf16x8* bp0 =
        (const bf16x8*)(lwt + (size_t)(nt * 16 + ccol) * IN_CH + ko);
    const bf16x8* bp1 =
        (const bf16x8*)(lwt + (size_t)(64 + nt * 16 + ccol) * IN_CH + ko);
#pragma unroll
    for (int kb = 0; kb < 4; ++kb) {
      acc0 = __builtin_amdgcn_mfma_f32_16x16x32_bf16(a[kb], bp0[kb * 4], acc0,
                                                     0, 0, 0);
      acc1 = __builtin_amdgcn_mfma_f32_16x16x32_bf16(a[kb], bp1[kb * 4], acc1,
                                                     0, 0, 0);
    }
#pragma unroll
    for (int rr = 0; rr < 4; ++rr) {
      int n = crow0 + rr;
      if (n < N)
        out[(size_t)n * OUT_CH + nt * 16 + ccol] =
            fmaf(acc0[rr], w0r[rr], acc1[rr] * w1r[rr]);
    }
  }
}

extern "C" void kernel_launch(void* const* d_in, const int* in_sizes, int n_in,
                              void* d_out, int out_size, void* d_ws,
                              size_t ws_size, hipStream_t stream) {
  const float* x = (const float*)d_in[0];
  const float* emb = (const float*)d_in[1];
  const float* lw = (const float*)d_in[2];
  const float* att_i = (const float*)d_in[3];
  const float* att_j = (const float*)d_in[4];
  const float* aei = (const float*)d_in[5];
  const float* aej = (const float*)d_in[6];
  const int* esrc = (const int*)d_in[7];
  const int* edst = (const int*)d_in[8];
  float* out = (float*)d_out;

  int N = in_sizes[0] / IN_CH;  // 50000
  int E = in_sizes[7];          // 1600000
  int nbkt = (N + 1023) >> BSHIFT;     // 49 dst partitions
  int nbin = (E + CHUNK - 1) / CHUNK;  // 782 bin blocks

  char* ws = (char*)d_ws;
  u64* wsum64 = (u64*)ws;                            // N u64
  u64* ptabs = wsum64 + N;                           // nbkt*SPLITS*1024 u64
  float2* si = (float2*)(ptabs + (size_t)nbkt * SPLITS * 1024);
  float2* sj = si + N;                               // N float2
  float* wself = (float*)(sj + N);                   // N f32
  float* u = wself + N;                              // 512 f32
  unsigned short* lwt = (unsigned short*)(u + 512);  // 16384 bf16 (32 KB)
  int* gcur = (int*)(lwt + 16384);                   // 256 ints
  u32* brecs = (u32*)(gcur + 256);                   // nbkt * cap u32 records

  size_t fixed = (size_t)((char*)brecs - ws);
  size_t avail = ws_size > fixed ? (ws_size - fixed) / 4 : 0;
  int cap = (int)(avail / (nbkt > 0 ? nbkt : 1));
  if (cap > CAPMAX) cap = CAPMAX;
  if (cap < 4096) cap = 4096;  // spill fallback keeps this correct anyway

  prep_kernel<<<dim3(66), dim3(256), 0, stream>>>(lw, att_i, att_j, lwt, u,
                                                  gcur);
  score_kernel<<<dim3((N + 3) / 4), dim3(256), 0, stream>>>(
      x, emb, u, aei, aej, si, sj, wself, wsum64, N);
  bin_kernel<<<dim3(nbin), dim3(256), 0, stream>>>(esrc, edst, si, sj, brecs,
                                                   gcur, wsum64, cap, E);
  acc_kernel<<<dim3(nbkt * SPLITS), dim3(256), 0, stream>>>(brecs, gcur, ptabs,
                                                            cap);
  gemm_out_kernel<<<dim3((N + 63) / 64), dim3(256), 0, stream>>>(
      x, lwt, wsum64, ptabs, wself, out, N);
}

// Round 3
// 171.460 us; speedup vs baseline: 1.2529x; 1.0306x over previous
//
#include <hip/hip_runtime.h>

#define IN_CH 128
#define OUT_CH 64
#define NEG_SLOPE 0.2f

#define CHUNK 2048      // edges per bin block
#define BSHIFT 10       // 1024 nodes per partition
#define NGEMM 391       // gemm-role blocks (782 row-tiles -> 2 each)
#define CAPMAX 36864    // records per partition region (mean 32.7K + ~23 sigma)
// p0 stored as 22-bit fixed point; u64 accumulate = (cnt<<32) | sum(fx22).
#define FIX22 4194304.0f

typedef short bf16x8 __attribute__((ext_vector_type(8)));
typedef float f32x4 __attribute__((ext_vector_type(4)));
typedef unsigned long long u64;
typedef unsigned int u32;

__device__ __forceinline__ unsigned short f2bf(float f) {
  union { float f; unsigned u; } v;
  v.f = f;
  unsigned r = v.u + 0x7FFF + ((v.u >> 16) & 1);  // RNE
  return (unsigned short)(r >> 16);
}

__device__ __forceinline__ float bf2f(unsigned short h) {
  union { unsigned u; float f; } v;
  v.u = (unsigned)h << 16;
  return v.f;
}

// ---------------------------------------------------------------------------
// Kernel 0 (prep): 66 blocks.
//  bid<64: lwt[c][k] = bf16(lw[k][c]) (transposed 32 KB bf16 B^T table).
//  bid 64/65: u_i / u_j (512 floats). bid 0 also zeroes bucket cursors.
// ---------------------------------------------------------------------------
__global__ __launch_bounds__(256) void prep_kernel(
    const float* __restrict__ lw, const float* __restrict__ att_i,
    const float* __restrict__ att_j, unsigned short* __restrict__ lwt,
    float* __restrict__ u, int* __restrict__ gcur) {
  const int bid = blockIdx.x;
  const int tid = threadIdx.x;
  if (bid == 0) gcur[tid] = 0;
  if (bid < 64) {
    int idx = bid * 256 + tid;  // 0..16383
    int k = idx >> 7;
    int c = idx & 127;
    lwt[(size_t)c * IN_CH + k] = f2bf(lw[idx]);
  } else {
    int which = bid - 64;  // 0 -> att_i, 1 -> att_j
    const float* att = which ? att_j : att_i;
    int k = tid & 127;
    int h = (tid >> 7) & 1;
    float v = 0.f;
#pragma unroll 8
    for (int d = 0; d < 64; ++d)
      v = fmaf(lw[(size_t)k * IN_CH + h * 64 + d], att[h * 64 + d], v);
    u[which * 256 + h * 128 + k] = v;
  }
}

// ---------------------------------------------------------------------------
// Kernel 1 (score): si/sj/wself from x,emb via precomputed u (L1-hot 2 KB).
// Seeds wsum64=0 (spill baseline). One wave per node.
// ---------------------------------------------------------------------------
__global__ __launch_bounds__(256) void score_kernel(
    const float* __restrict__ x, const float* __restrict__ emb,
    const float* __restrict__ u, const float* __restrict__ aei,
    const float* __restrict__ aej, float2* __restrict__ si,
    float2* __restrict__ sj, float* __restrict__ wself,
    u64* __restrict__ wsum64, int N) {
  const int tid = threadIdx.x;
  const int wave = tid >> 6;
  const int lane = tid & 63;
  const int n = blockIdx.x * 4 + wave;
  if (n >= N) return;

  float x0 = x[(size_t)n * IN_CH + lane];
  float x1 = x[(size_t)n * IN_CH + 64 + lane];
  float em = emb[(size_t)n * OUT_CH + lane];

  float v_si0 = fmaf(x0, u[lane], fmaf(x1, u[64 + lane], em * aei[lane]));
  float v_si1 =
      fmaf(x0, u[128 + lane], fmaf(x1, u[192 + lane], em * aei[64 + lane]));
  float v_sj0 =
      fmaf(x0, u[256 + lane], fmaf(x1, u[320 + lane], em * aej[lane]));
  float v_sj1 =
      fmaf(x0, u[384 + lane], fmaf(x1, u[448 + lane], em * aej[64 + lane]));

#pragma unroll
  for (int off = 32; off > 0; off >>= 1) {
    v_si0 += __shfl_xor(v_si0, off, 64);
    v_si1 += __shfl_xor(v_si1, off, 64);
    v_sj0 += __shfl_xor(v_sj0, off, 64);
    v_sj1 += __shfl_xor(v_sj1, off, 64);
  }

  if (lane == 0) {
    si[n] = make_float2(v_si0, v_si1);
    sj[n] = make_float2(v_sj0, v_sj1);
    float a0 = v_si0 + v_sj0;
    float a1 = v_si1 + v_sj1;
    a0 = a0 > 0.f ? a0 : NEG_SLOPE * a0;
    a1 = a1 > 0.f ? a1 : NEG_SLOPE * a1;
    wself[n] = 1.f / (1.f + __expf(a1 - a0));
    wsum64[n] = 0ull;  // spill-fallback baseline
  }
}

// ---------------------------------------------------------------------------
// Kernel 2 (bin + gemm fused, role-split). LDS 9.25 KB.
//  bin blocks [0,nbin): counting-sort a 2048-edge chunk into 49 dst-range
//    partitions: hist -> single-wave shuffle scan -> LDS record scatter ->
//    coalesced writeout via 6-iter binary search. Record =
//    (dlocal10 << 22) | fx22(p0). Overflow -> packed u64 atomic into wsum64.
//  gemm blocks [nbin,..): xh(bf16) = x @ lin_w via mfma_16x16x32_bf16, B^T
//    read from the L1-resident 32 KB lwt table. GEMM issue hides in the
//    bin blocks' latency stalls (overlapped roles, round-0-proven).
// ---------------------------------------------------------------------------
__global__ __launch_bounds__(256) void bin_gemm_kernel(
    const float* __restrict__ x, const unsigned short* __restrict__ lwt,
    const int* __restrict__ esrc, const int* __restrict__ edst,
    const float2* __restrict__ si, const float2* __restrict__ sj,
    unsigned short* __restrict__ xhb, u64* __restrict__ wsum64,
    u32* __restrict__ brecs, int* __restrict__ gcur, int cap, int nbin, int N,
    int E) {
  __shared__ u32 recs[CHUNK];  // 8 KB
  __shared__ int hist[64];
  __shared__ int scan[64];
  __shared__ int gbase[64];
  __shared__ int cur[64];
  const int bid = blockIdx.x;
  const int tid = threadIdx.x;
  const int wave = tid >> 6;
  const int lane = tid & 63;

  if (bid < nbin) {
    // ================= bin role =================
    if (tid < 64) hist[tid] = 0;
    __syncthreads();

    const long e0 = (long)bid * CHUNK;
    const int cnt = (int)min((long)CHUNK, (long)E - e0);

    for (int r = tid; r < cnt; r += 256)
      atomicAdd(&hist[edst[e0 + r] >> BSHIFT], 1);
    __syncthreads();

    // wave-0 shuffle prefix scan over 64 partitions
    if (tid < 64) {
      int h = hist[tid];
      int v = h;
#pragma unroll
      for (int off = 1; off < 64; off <<= 1) {
        int t = __shfl_up(v, off, 64);
        if (tid >= off) v += t;
      }
      int excl = v - h;  // exclusive scan
      scan[tid] = excl;
      cur[tid] = excl;
      gbase[tid] = (h > 0) ? atomicAdd(&gcur[tid], h) : 0;
    }
    __syncthreads();

    // per-edge score -> scatter record into LDS grouped by partition
    for (int r = tid; r < cnt; r += 256) {
      long e = e0 + r;
      int s = esrc[e];
      int d = edst[e];
      float2 aa = si[s];
      float2 bb = sj[d];
      float a0 = aa.x + bb.x;
      float a1 = aa.y + bb.y;
      a0 = a0 > 0.f ? a0 : NEG_SLOPE * a0;
      a1 = a1 > 0.f ? a1 : NEG_SLOPE * a1;
      float p0 = 1.f / (1.f + __expf(a1 - a0));
      u32 fx = (u32)fminf(p0 * FIX22 + 0.5f, 4194303.0f);  // 22-bit
      int pos = atomicAdd(&cur[d >> BSHIFT], 1);
      recs[pos] = ((u32)(d & 1023) << 22) | fx;
    }
    __syncthreads();

    // coalesced writeout; partition via 6-iter binary search over scan
    for (int p = tid; p < cnt; p += 256) {
      int lo = 0, hi = 63;
#pragma unroll
      for (int it = 0; it < 6; ++it) {
        int mid = (lo + hi + 1) >> 1;
        if (scan[mid] <= p) lo = mid; else hi = mid - 1;
      }
      int b = lo;
      int gofs = gbase[b] + (p - scan[b]);
      u32 rec = recs[p];
      if (gofs < cap) {
        brecs[(size_t)b * cap + gofs] = rec;
      } else {  // rare spill: packed u64 device atomic
        atomicAdd(&wsum64[(b << BSHIFT) + (int)(rec >> 22)],
                  (1ull << 32) | (u64)(rec & 0x3FFFFFu));
      }
    }
  } else {
    // ================= gemm role (no LDS use) =================
    const int g = bid - nbin;
    const int ntiles = (N + 63) / 64;
    const int ko = (lane >> 4) * 8;
    const int ccol = lane & 15;
    for (int tile = g; tile < ntiles; tile += NGEMM) {
      const int row0 = tile * 64 + wave * 16;
      int arow = row0 + (lane & 15);
      if (arow >= N) arow = N - 1;  // clamped read; stores guarded
      const float* ap = x + (size_t)arow * IN_CH + ko;
      bf16x8 a[4];
#pragma unroll
      for (int kb = 0; kb < 4; ++kb) {
        float4 f0 = *(const float4*)(ap + kb * 32);
        float4 f1 = *(const float4*)(ap + kb * 32 + 4);
        bf16x8 t;
        t[0] = (short)f2bf(f0.x); t[1] = (short)f2bf(f0.y);
        t[2] = (short)f2bf(f0.z); t[3] = (short)f2bf(f0.w);
        t[4] = (short)f2bf(f1.x); t[5] = (short)f2bf(f1.y);
        t[6] = (short)f2bf(f1.z); t[7] = (short)f2bf(f1.w);
        a[kb] = t;
      }
      const int crow0 = row0 + (lane >> 4) * 4;
#pragma unroll
      for (int nt = 0; nt < 8; ++nt) {
        f32x4 acc = {0.f, 0.f, 0.f, 0.f};
        const bf16x8* bp =
            (const bf16x8*)(lwt + (size_t)(nt * 16 + ccol) * IN_CH + ko);
        acc = __builtin_amdgcn_mfma_f32_16x16x32_bf16(a[0], bp[0], acc, 0, 0, 0);
        acc = __builtin_amdgcn_mfma_f32_16x16x32_bf16(a[1], bp[4], acc, 0, 0, 0);
        acc = __builtin_amdgcn_mfma_f32_16x16x32_bf16(a[2], bp[8], acc, 0, 0, 0);
        acc = __builtin_amdgcn_mfma_f32_16x16x32_bf16(a[3], bp[12], acc, 0, 0, 0);
#pragma unroll
        for (int rr = 0; rr < 4; ++rr) {
          int n = crow0 + rr;
          if (n < N) xhb[(size_t)n * IN_CH + nt * 16 + ccol] = f2bf(acc[rr]);
        }
      }
    }
  }
}

// ---------------------------------------------------------------------------
// Kernel 3 (reduce + out): 196 blocks x 1024. Block (p,q) filters partition
// p's records for sub-bucket q (dlocal>>8 == q), accumulates into a
// 256-entry u64 LDS table (one LDS atomic per matching record), then
// computes out for its 256 nodes from bf16 xh + weights.
// ---------------------------------------------------------------------------
__global__ __launch_bounds__(1024) void reduce_out_kernel(
    const unsigned short* __restrict__ xhb, const u64* __restrict__ wsum64,
    const float* __restrict__ wself, const u32* __restrict__ brecs,
    const int* __restrict__ gcur, int cap, float* __restrict__ out, int N) {
  __shared__ u64 tab[256];
  const int bid = blockIdx.x;
  const int p = bid >> 2;   // partition 0..48
  const int q = bid & 3;    // sub-bucket 0..3
  const int tid = threadIdx.x;

  if (tid < 256) tab[tid] = 0ull;
  __syncthreads();

  const int cnt = min(gcur[p], cap);
  const u32* rp = brecs + (size_t)p * cap;
  for (int r = tid; r < cnt; r += 1024) {
    u32 rec = rp[r];
    if ((int)(rec >> 30) == q)
      atomicAdd(&tab[(rec >> 22) & 255], (1ull << 32) | (u64)(rec & 0x3FFFFFu));
  }
  __syncthreads();

  const int n0 = (p << BSHIFT) + (q << 8);
  const int nmax = min(256, N - n0);
  if (nmax <= 0) return;
  for (int t = tid; t < nmax * 16; t += 1024) {
    int ln = t >> 4;
    int n = n0 + ln;
    int c4 = (t & 15) << 2;
    u64 acc = tab[ln] + wsum64[n];  // spill baseline shares the packing
    float cnt_f = (float)(u32)(acc >> 32);
    float s0 = (float)(u32)(acc & 0xFFFFFFFFu) * (1.0f / FIX22);
    float ps = wself[n];
    float w0 = 0.5f * (s0 + ps);
    float w1 = 0.5f * ((cnt_f - s0) + (1.f - ps));
    ushort4 h0 = *(const ushort4*)&xhb[(size_t)n * IN_CH + c4];
    ushort4 h1 = *(const ushort4*)&xhb[(size_t)n * IN_CH + 64 + c4];
    float4 o;
    o.x = fmaf(bf2f(h0.x), w0, bf2f(h1.x) * w1);
    o.y = fmaf(bf2f(h0.y), w0, bf2f(h1.y) * w1);
    o.z = fmaf(bf2f(h0.z), w0, bf2f(h1.z) * w1);
    o.w = fmaf(bf2f(h0.w), w0, bf2f(h1.w) * w1);
    *(float4*)&out[(size_t)n * OUT_CH + c4] = o;
  }
}

extern "C" void kernel_launch(void* const* d_in, const int* in_sizes, int n_in,
                              void* d_out, int out_size, void* d_ws,
                              size_t ws_size, hipStream_t stream) {
  const float* x = (const float*)d_in[0];
  const float* emb = (const float*)d_in[1];
  const float* lw = (const float*)d_in[2];
  const float* att_i = (const float*)d_in[3];
  const float* att_j = (const float*)d_in[4];
  const float* aei = (const float*)d_in[5];
  const float* aej = (const float*)d_in[6];
  const int* esrc = (const int*)d_in[7];
  const int* edst = (const int*)d_in[8];
  float* out = (float*)d_out;

  int N = in_sizes[0] / IN_CH;  // 50000
  int E = in_sizes[7];          // 1600000
  int nbkt = (N + 1023) >> BSHIFT;     // 49 dst partitions
  int nbin = (E + CHUNK - 1) / CHUNK;  // 782 bin blocks

  char* ws = (char*)d_ws;
  u64* wsum64 = (u64*)ws;                            // N u64
  float2* si = (float2*)(wsum64 + N);                // N float2
  float2* sj = si + N;                               // N float2
  float* wself = (float*)(sj + N);                   // N f32
  float* u = wself + N;                              // 512 f32
  unsigned short* lwt = (unsigned short*)(u + 512);  // 16384 bf16 (32 KB)
  unsigned short* xhb = lwt + 16384;                 // N*128 bf16 (12.8 MB)
  int* gcur = (int*)(xhb + (size_t)N * IN_CH);       // 256 ints
  u32* brecs = (u32*)(gcur + 256);                   // nbkt * cap u32 records

  size_t fixed = (size_t)((char*)brecs - ws);
  size_t avail = ws_size > fixed ? (ws_size - fixed) / 4 : 0;
  int cap = (int)(avail / (nbkt > 0 ? nbkt : 1));
  if (cap > CAPMAX) cap = CAPMAX;
  if (cap < 4096) cap = 4096;  // spill fallback keeps this correct anyway

  prep_kernel<<<dim3(66), dim3(256), 0, stream>>>(lw, att_i, att_j, lwt, u,
                                                  gcur);
  score_kernel<<<dim3((N + 3) / 4), dim3(256), 0, stream>>>(
      x, emb, u, aei, aej, si, sj, wself, wsum64, N);
  bin_gemm_kernel<<<dim3(nbin + NGEMM), dim3(256), 0, stream>>>(
      x, lwt, esrc, edst, si, sj, xhb, wsum64, brecs, gcur, cap, nbin, N, E);
  reduce_out_kernel<<<dim3(nbkt * 4), dim3(1024), 0, stream>>>(
      xhb, wsum64, wself, brecs, gcur, cap, out, N);
}